// Round 1
// 1565.785 us; speedup vs baseline: 1.3590x; 1.3590x over previous
//
#include <hip/hip_runtime.h>

typedef unsigned short u16;
typedef __attribute__((ext_vector_type(8))) short bf16x8;
typedef __attribute__((ext_vector_type(4))) float f32x4;

__device__ __forceinline__ u16 f2bf(float f) {
  union { float f; unsigned u; } v; v.f = f;
  unsigned r = (v.u + 0x7fffu + ((v.u >> 16) & 1u)) >> 16;
  return (u16)r;
}
__device__ __forceinline__ float bf2f(u16 u) {
  union { unsigned u; float f; } v; v.u = ((unsigned)u) << 16;
  return v.f;
}
__device__ __forceinline__ void split2(float f, u16& hi, u16& lo) {
  hi = f2bf(f);
  lo = f2bf(f - bf2f(hi));
}

// ---------------- async global->LDS staging ---------------------------------
typedef const unsigned int __attribute__((address_space(1)))* gptr_t;
typedef unsigned int __attribute__((address_space(3)))* lptr_t;

__device__ __forceinline__ void gl16(const u16* g, u16* l) {
#if __has_builtin(__builtin_amdgcn_global_load_lds)
  __builtin_amdgcn_global_load_lds((gptr_t)g, (lptr_t)l, 16, 0, 0);
#else
  *reinterpret_cast<uint4*>(l) = *reinterpret_cast<const uint4*>(g);
#endif
}

// LDS tiles are linear [128 rows][32 k] bf16 (8 KB) — required by global_load_lds
// (wave-uniform base + lane*16). dest byte offset == tid*16, trivially linear.

// ---------------- MFMA cores -------------------------------------------------
__device__ __forceinline__ void mf_bf16(const u16* __restrict__ sA,
    const u16* __restrict__ sB, f32x4 (&acc)[4][4], int wm, int wn, int lr, int lk) {
  bf16x8 a[4], b[4];
#pragma unroll
  for (int i = 0; i < 4; i++) {
    a[i] = *reinterpret_cast<const bf16x8*>(&sA[(wm + i * 16 + lr) * 32 + lk]);
    b[i] = *reinterpret_cast<const bf16x8*>(&sB[(wn + i * 16 + lr) * 32 + lk]);
  }
#pragma unroll
  for (int i = 0; i < 4; i++)
#pragma unroll
    for (int j = 0; j < 4; j++)
      acc[i][j] = __builtin_amdgcn_mfma_f32_16x16x32_bf16(a[i], b[j], acc[i][j], 0, 0, 0);
}

__device__ __forceinline__ void mf_hilo(const u16* __restrict__ sAhp,
    const u16* __restrict__ sAlp, const u16* __restrict__ sBhp,
    const u16* __restrict__ sBlp, f32x4 (&acc)[4][4], int wm, int wn, int lr, int lk) {
  bf16x8 ah[4], al[4], bh[4], bl[4];
#pragma unroll
  for (int i = 0; i < 4; i++) {
    ah[i] = *reinterpret_cast<const bf16x8*>(&sAhp[(wm + i * 16 + lr) * 32 + lk]);
    al[i] = *reinterpret_cast<const bf16x8*>(&sAlp[(wm + i * 16 + lr) * 32 + lk]);
    bh[i] = *reinterpret_cast<const bf16x8*>(&sBhp[(wn + i * 16 + lr) * 32 + lk]);
    bl[i] = *reinterpret_cast<const bf16x8*>(&sBlp[(wn + i * 16 + lr) * 32 + lk]);
  }
#pragma unroll
  for (int i = 0; i < 4; i++)
#pragma unroll
    for (int j = 0; j < 4; j++) {
      f32x4 t = acc[i][j];
      t = __builtin_amdgcn_mfma_f32_16x16x32_bf16(al[i], bh[j], t, 0, 0, 0);
      t = __builtin_amdgcn_mfma_f32_16x16x32_bf16(ah[i], bl[j], t, 0, 0, 0);
      t = __builtin_amdgcn_mfma_f32_16x16x32_bf16(ah[i], bh[j], t, 0, 0, 0);
      acc[i][j] = t;  // lo*lo dropped: ~2^-16 relative, negligible
    }
}

#define HILO_PREAMBLE \
  __shared__ __align__(16) u16 sAh[2][4096], sAl[2][4096], sBh[2][4096], sBl[2][4096]; \
  int tid = threadIdx.x, lane = tid & 63; \
  int wm = ((tid >> 6) & 1) << 6, wn = (tid >> 7) << 6; \
  int lr = lane & 15, lk = (lane >> 4) << 3; \
  int er = (lane >> 4) << 2, ec = lane & 15; \
  int r = tid >> 2, c = (tid & 3) << 3; \
  int so = r * 32 + c, so2 = so + 2048; \
  f32x4 acc[4][4] = {};

#define STAGE_HILO(buf) \
  gl16(pAh + ko, &sAh[buf][so]); gl16(pAh2 + ko, &sAh[buf][so2]); \
  gl16(pAl + ko, &sAl[buf][so]); gl16(pAl2 + ko, &sAl[buf][so2]); \
  gl16(pBh + ko, &sBh[buf][so]); gl16(pBh2 + ko, &sBh[buf][so2]); \
  gl16(pBl + ko, &sBl[buf][so]); gl16(pBl2 + ko, &sBl[buf][so2]);

#define BF16_PREAMBLE \
  __shared__ __align__(16) u16 sA[2][4096], sB[2][4096]; \
  int tid = threadIdx.x, lane = tid & 63; \
  int wm = ((tid >> 6) & 1) << 6, wn = (tid >> 7) << 6; \
  int lr = lane & 15, lk = (lane >> 4) << 3; \
  int er = (lane >> 4) << 2, ec = lane & 15; \
  int r = tid >> 2, c = (tid & 3) << 3; \
  int so = r * 32 + c, so2 = so + 2048; \
  f32x4 acc[4][4] = {};

#define STAGE_AB(buf) \
  gl16(pA + ko, &sA[buf][so]); gl16(pA2 + ko, &sA[buf][so2]); \
  gl16(pB + ko, &sB[buf][so]); gl16(pB2 + ko, &sB[buf][so2]);

// ---------------- weight conversion kernels ----------------------------------
// fp32 W[K][N] (expert stride K*N via blockIdx.z) -> bf16 T[N][K]; 64K x 32N tiles
__global__ __launch_bounds__(256) void convt_bf16(const float* __restrict__ W,
    u16* __restrict__ T, int K, int N) {
  __shared__ float t[64][33];
  long eo = (long)blockIdx.z * K * N;
  int k0 = blockIdx.y << 6, n0 = blockIdx.x << 5;
  int tid = threadIdx.x;
  int r = tid >> 3, cc = (tid & 7) << 2;
  const float* src = W + eo + (long)(k0 + r) * N + n0 + cc;
  float4 a = *reinterpret_cast<const float4*>(src);
  float4 b = *reinterpret_cast<const float4*>(src + (long)32 * N);
  t[r][cc] = a.x; t[r][cc + 1] = a.y; t[r][cc + 2] = a.z; t[r][cc + 3] = a.w;
  t[r + 32][cc] = b.x; t[r + 32][cc + 1] = b.y; t[r + 32][cc + 2] = b.z; t[r + 32][cc + 3] = b.w;
  __syncthreads();
  int n = tid >> 3, kc = (tid & 7) << 3;
  __align__(16) u16 h[8];
#pragma unroll
  for (int i = 0; i < 8; i++) h[i] = f2bf(t[kc + i][n]);
  *reinterpret_cast<uint4*>(&T[eo + (long)(n0 + n) * K + k0 + kc]) =
      *reinterpret_cast<uint4*>(h);
}

// fp32 W[K][N] -> hi/lo bf16 T[N][K]
__global__ __launch_bounds__(256) void convt_split(const float* __restrict__ W,
    u16* __restrict__ Thi, u16* __restrict__ Tlo, int K, int N) {
  __shared__ float t[64][33];
  int k0 = blockIdx.y << 6, n0 = blockIdx.x << 5;
  int tid = threadIdx.x;
  int r = tid >> 3, cc = (tid & 7) << 2;
  const float* src = W + (long)(k0 + r) * N + n0 + cc;
  float4 a = *reinterpret_cast<const float4*>(src);
  float4 b = *reinterpret_cast<const float4*>(src + (long)32 * N);
  t[r][cc] = a.x; t[r][cc + 1] = a.y; t[r][cc + 2] = a.z; t[r][cc + 3] = a.w;
  t[r + 32][cc] = b.x; t[r + 32][cc + 1] = b.y; t[r + 32][cc + 2] = b.z; t[r + 32][cc + 3] = b.w;
  __syncthreads();
  int n = tid >> 3, kc = (tid & 7) << 3;
  __align__(16) u16 h[8], l[8];
#pragma unroll
  for (int i = 0; i < 8; i++) split2(t[kc + i][n], h[i], l[i]);
  long o = (long)(n0 + n) * K + k0 + kc;
  *reinterpret_cast<uint4*>(&Thi[o]) = *reinterpret_cast<uint4*>(h);
  *reinterpret_cast<uint4*>(&Tlo[o]) = *reinterpret_cast<uint4*>(l);
}

// ---------------- elementwise / small kernels -------------------------------

// rmsnorm row (D=2048 fp32) -> hi/lo bf16 (attention input)
__global__ __launch_bounds__(256) void rmsnorm_split(const float* __restrict__ x,
    const float* __restrict__ w, u16* __restrict__ ohi, u16* __restrict__ olo) {
  __shared__ float lbuf[4];
  int tid = threadIdx.x;
  long base = (long)blockIdx.x * 2048;
  float4 v0 = *reinterpret_cast<const float4*>(&x[base + tid * 8]);
  float4 v1 = *reinterpret_cast<const float4*>(&x[base + tid * 8 + 4]);
  float ss = v0.x * v0.x + v0.y * v0.y + v0.z * v0.z + v0.w * v0.w +
             v1.x * v1.x + v1.y * v1.y + v1.z * v1.z + v1.w * v1.w;
  for (int off = 32; off; off >>= 1) ss += __shfl_down(ss, off);
  if ((tid & 63) == 0) lbuf[tid >> 6] = ss;
  __syncthreads();
  float tot = lbuf[0] + lbuf[1] + lbuf[2] + lbuf[3];
  float scale = 1.0f / sqrtf(tot * (1.0f / 2048.0f) + 1e-6f);
  float4 w0 = *reinterpret_cast<const float4*>(&w[tid * 8]);
  float4 w1 = *reinterpret_cast<const float4*>(&w[tid * 8 + 4]);
  float f[8] = {v0.x * scale * w0.x, v0.y * scale * w0.y, v0.z * scale * w0.z,
                v0.w * scale * w0.w, v1.x * scale * w1.x, v1.y * scale * w1.y,
                v1.z * scale * w1.z, v1.w * scale * w1.w};
  __align__(16) u16 h[8], l[8];
#pragma unroll
  for (int i = 0; i < 8; i++) split2(f[i], h[i], l[i]);
  *reinterpret_cast<uint4*>(&ohi[base + tid * 8]) = *reinterpret_cast<uint4*>(h);
  *reinterpret_cast<uint4*>(&olo[base + tid * 8]) = *reinterpret_cast<uint4*>(l);
}

// rmsnorm row -> bf16 (MoE input)
__global__ __launch_bounds__(256) void rmsnorm_bf16(const float* __restrict__ x,
    const float* __restrict__ w, u16* __restrict__ o) {
  __shared__ float lbuf[4];
  int tid = threadIdx.x;
  long base = (long)blockIdx.x * 2048;
  float4 v0 = *reinterpret_cast<const float4*>(&x[base + tid * 8]);
  float4 v1 = *reinterpret_cast<const float4*>(&x[base + tid * 8 + 4]);
  float ss = v0.x * v0.x + v0.y * v0.y + v0.z * v0.z + v0.w * v0.w +
             v1.x * v1.x + v1.y * v1.y + v1.z * v1.z + v1.w * v1.w;
  for (int off = 32; off; off >>= 1) ss += __shfl_down(ss, off);
  if ((tid & 63) == 0) lbuf[tid >> 6] = ss;
  __syncthreads();
  float tot = lbuf[0] + lbuf[1] + lbuf[2] + lbuf[3];
  float scale = 1.0f / sqrtf(tot * (1.0f / 2048.0f) + 1e-6f);
  float4 w0 = *reinterpret_cast<const float4*>(&w[tid * 8]);
  float4 w1 = *reinterpret_cast<const float4*>(&w[tid * 8 + 4]);
  ushort4 o0, o1;
  o0.x = f2bf(v0.x * scale * w0.x); o0.y = f2bf(v0.y * scale * w0.y);
  o0.z = f2bf(v0.z * scale * w0.z); o0.w = f2bf(v0.w * scale * w0.w);
  o1.x = f2bf(v1.x * scale * w1.x); o1.y = f2bf(v1.y * scale * w1.y);
  o1.z = f2bf(v1.z * scale * w1.z); o1.w = f2bf(v1.w * scale * w1.w);
  *reinterpret_cast<ushort4*>(&o[base + tid * 8]) = o0;
  *reinterpret_cast<ushort4*>(&o[base + tid * 8 + 4]) = o1;
}

// RoPE on fp32 [b][s][nh][128] -> hi/lo bf16 (same layout); one 64-lane unit/(b,s,head)
__global__ __launch_bounds__(256) void rope_split(const float* __restrict__ x, int nh,
    u16* __restrict__ ohi, u16* __restrict__ olo) {
  int unit = blockIdx.x * 4 + (threadIdx.x >> 6);
  int lane = threadIdx.x & 63;
  int s = (unit / nh) & 1023;
  const float* p = x + (long)unit * 128;
  float x1 = p[lane], x2 = p[lane + 64];
  float ang = (float)s * exp2f((float)lane * (-13.287712379549449f / 64.0f));
  float sn, cs;
  sincosf(ang, &sn, &cs);
  long o = (long)unit * 128 + lane;
  u16 hh, ll;
  split2(x1 * cs - x2 * sn, hh, ll);
  ohi[o] = hh; olo[o] = ll;
  split2(x1 * sn + x2 * cs, hh, ll);
  ohi[o + 64] = hh; olo[o + 64] = ll;
}

// fp32 transpose [R][C] -> hi/lo bf16 [C][R] per batch (blockIdx.z)
__global__ __launch_bounds__(256) void transpose_split(const float* __restrict__ in,
    u16* __restrict__ ohi, u16* __restrict__ olo, int R, int C) {
  __shared__ float tile[32][33];
  long bo = (long)blockIdx.z * R * C;
  int r0 = blockIdx.y * 32, c0 = blockIdx.x * 32;
  int r = threadIdx.x >> 5, c = threadIdx.x & 31;
#pragma unroll
  for (int i = 0; i < 4; i++)
    tile[r + i * 8][c] = in[bo + (long)(r0 + r + i * 8) * C + c0 + c];
  __syncthreads();
#pragma unroll
  for (int i = 0; i < 4; i++) {
    u16 hh, ll;
    split2(tile[c][r + i * 8], hh, ll);
    long o = bo + (long)(c0 + r + i * 8) * R + r0 + c;
    ohi[o] = hh; olo[o] = ll;
  }
}

// causal softmax: fp32 scores row (len 1024) -> hi/lo bf16 probs (zero-padded to tile)
__global__ __launch_bounds__(256) void softmax_split(const float* __restrict__ sc,
    u16* __restrict__ phi, u16* __restrict__ plo) {
  __shared__ float lbuf[4];
  long row = blockIdx.x;
  int q = (int)(row & 1023);
  const float* p = sc + row * 1024;
  int tid = threadIdx.x;
  int valid = q + 1;
  int pend = (q & ~127) + 128;
  float v[4];
  float mx = -1e30f;
#pragma unroll
  for (int i = 0; i < 4; i++) {
    int t = tid + i * 256;
    float f = (t < valid) ? p[t] : -1e30f;
    v[i] = f;
    mx = fmaxf(mx, f);
  }
  for (int off = 32; off; off >>= 1) mx = fmaxf(mx, __shfl_down(mx, off));
  if ((tid & 63) == 0) lbuf[tid >> 6] = mx;
  __syncthreads();
  float m = fmaxf(fmaxf(lbuf[0], lbuf[1]), fmaxf(lbuf[2], lbuf[3]));
  __syncthreads();
  float sum = 0.0f;
#pragma unroll
  for (int i = 0; i < 4; i++) {
    int t = tid + i * 256;
    float e = (t < valid) ? expf(v[i] - m) : 0.0f;
    v[i] = e;
    sum += e;
  }
  for (int off = 32; off; off >>= 1) sum += __shfl_down(sum, off);
  if ((tid & 63) == 0) lbuf[tid >> 6] = sum;
  __syncthreads();
  float inv = 1.0f / (lbuf[0] + lbuf[1] + lbuf[2] + lbuf[3]);
#pragma unroll
  for (int i = 0; i < 4; i++) {
    int t = tid + i * 256;
    if (t < valid) {
      u16 hh, ll;
      split2(v[i] * inv, hh, ll);
      phi[row * 1024 + t] = hh; plo[row * 1024 + t] = ll;
    } else if (t < pend) {
      phi[row * 1024 + t] = 0; plo[row * 1024 + t] = 0;
    }
  }
}

// router: fp32 rmsnorm of out row + fp32 logits, top-2, gates, counts
__global__ __launch_bounds__(256) void router_kernel(const float* __restrict__ xo,
    const float* __restrict__ w, const float* __restrict__ Wr,
    int* __restrict__ tok_e, float* __restrict__ tok_g, int* __restrict__ counts) {
  __shared__ float lbuf[32];
  int tid = threadIdx.x;
  long base = (long)blockIdx.x * 2048;
  float4 v0 = *reinterpret_cast<const float4*>(&xo[base + tid * 8]);
  float4 v1 = *reinterpret_cast<const float4*>(&xo[base + tid * 8 + 4]);
  float ss = v0.x * v0.x + v0.y * v0.y + v0.z * v0.z + v0.w * v0.w +
             v1.x * v1.x + v1.y * v1.y + v1.z * v1.z + v1.w * v1.w;
  for (int off = 32; off; off >>= 1) ss += __shfl_down(ss, off);
  if ((tid & 63) == 0) lbuf[tid >> 6] = ss;
  __syncthreads();
  float tot = lbuf[0] + lbuf[1] + lbuf[2] + lbuf[3];
  float scale = 1.0f / sqrtf(tot * (1.0f / 2048.0f) + 1e-6f);
  __syncthreads();
  float4 w0 = *reinterpret_cast<const float4*>(&w[tid * 8]);
  float4 w1 = *reinterpret_cast<const float4*>(&w[tid * 8 + 4]);
  float h[8] = {v0.x * scale * w0.x, v0.y * scale * w0.y, v0.z * scale * w0.z,
                v0.w * scale * w0.w, v1.x * scale * w1.x, v1.y * scale * w1.y,
                v1.z * scale * w1.z, v1.w * scale * w1.w};
  float part[8] = {0, 0, 0, 0, 0, 0, 0, 0};
#pragma unroll
  for (int j = 0; j < 8; j++) {
    const float* wr = Wr + (long)(tid * 8 + j) * 8;
    float4 a = *reinterpret_cast<const float4*>(wr);
    float4 b = *reinterpret_cast<const float4*>(wr + 4);
    part[0] += h[j] * a.x; part[1] += h[j] * a.y;
    part[2] += h[j] * a.z; part[3] += h[j] * a.w;
    part[4] += h[j] * b.x; part[5] += h[j] * b.y;
    part[6] += h[j] * b.z; part[7] += h[j] * b.w;
  }
#pragma unroll
  for (int e = 0; e < 8; e++) {
    float s = part[e];
    for (int off = 32; off; off >>= 1) s += __shfl_down(s, off);
    if ((tid & 63) == 0) lbuf[(tid >> 6) * 8 + e] = s;
  }
  __syncthreads();
  if (tid == 0) {
    float lg[8];
#pragma unroll
    for (int e = 0; e < 8; e++)
      lg[e] = lbuf[e] + lbuf[8 + e] + lbuf[16 + e] + lbuf[24 + e];
    int e1 = 0;
    for (int e = 1; e < 8; e++) if (lg[e] > lg[e1]) e1 = e;
    int e2 = -1;
    for (int e = 0; e < 8; e++) if (e != e1 && (e2 < 0 || lg[e] > lg[e2])) e2 = e;
    float ex = __expf(lg[e2] - lg[e1]);
    float g1 = 1.0f / (1.0f + ex);
    tok_e[blockIdx.x * 2] = e1; tok_e[blockIdx.x * 2 + 1] = e2;
    tok_g[blockIdx.x * 2] = g1; tok_g[blockIdx.x * 2 + 1] = 1.0f - g1;
    atomicAdd(&counts[e1], 1);
    atomicAdd(&counts[e2], 1);
  }
}

__global__ void scan8(const int* __restrict__ counts, int* __restrict__ offsets,
                      int* __restrict__ cursor) {
  if (threadIdx.x == 0) {
    int off = 0;
    for (int e = 0; e < 8; e++) { offsets[e] = off; off += counts[e]; cursor[e] = 0; }
  }
}

__global__ __launch_bounds__(256) void fill_lists(const int* __restrict__ tok_e,
    const float* __restrict__ tok_g, const int* __restrict__ offsets,
    int* __restrict__ cursor, int* __restrict__ ltok, float* __restrict__ lgate) {
  int idx = blockIdx.x * 256 + threadIdx.x;  // 4096 slots
  int token = idx >> 1;
  int e = tok_e[idx];
  float g = tok_g[idx];
  int pos = atomicAdd(&cursor[e], 1);
  int j = offsets[e] + pos;
  ltok[j] = token;
  lgate[j] = g;
}

// ---------------- split (hi/lo) GEMMs, global_load_lds + 2-phase prefetch ---

// C[M][N] (fp32, +resid) = (Ahi+Alo)[M][K] @ (Bhi+Blo)[N][K]^T
__global__ __launch_bounds__(256) void gemm_hilo(
    const u16* __restrict__ Ahi, const u16* __restrict__ Alo, long ldA,
    const u16* __restrict__ Bhi, const u16* __restrict__ Blo, long ldB,
    const float* __restrict__ resid, float* __restrict__ C, long ldC, int Ksize) {
  HILO_PREAMBLE
  int m0 = blockIdx.y << 7, n0 = blockIdx.x << 7;
  const u16* pAh = Ahi + (long)(m0 + r) * ldA + c;  const u16* pAh2 = pAh + 64 * ldA;
  const u16* pAl = Alo + (long)(m0 + r) * ldA + c;  const u16* pAl2 = pAl + 64 * ldA;
  const u16* pBh = Bhi + (long)(n0 + r) * ldB + c;  const u16* pBh2 = pBh + 64 * ldB;
  const u16* pBl = Blo + (long)(n0 + r) * ldB + c;  const u16* pBl2 = pBl + 64 * ldB;
  { int ko = 0; STAGE_HILO(0) }
  __syncthreads();
  int cur = 0;
  for (int k0 = 0; k0 < Ksize; k0 += 32) {
    if (k0 + 32 < Ksize) { int ko = k0 + 32; STAGE_HILO(cur ^ 1) }
    mf_hilo(sAh[cur], sAl[cur], sBh[cur], sBl[cur], acc, wm, wn, lr, lk);
    __syncthreads();
    cur ^= 1;
  }
#pragma unroll
  for (int i = 0; i < 4; i++)
#pragma unroll
    for (int j = 0; j < 4; j++)
#pragma unroll
      for (int rr = 0; rr < 4; rr++) {
        long idx = (long)(m0 + wm + i * 16 + er + rr) * ldC + n0 + wn + j * 16 + ec;
        float v = acc[i][j][rr];
        C[idx] = resid ? resid[idx] + v : v;
      }
}

// scores slab: [bhloc][q][t] = (q . k) * DK^-0.5, lower-triangular tile grid
__global__ __launch_bounds__(256) void gemm_qk(
    const u16* __restrict__ qhi, const u16* __restrict__ qlo,
    const u16* __restrict__ khi, const u16* __restrict__ klo,
    float* __restrict__ sc, int bh0) {
  HILO_PREAMBLE
  int idx = blockIdx.x, mi = 0;
  while ((mi + 1) * (mi + 2) / 2 <= idx) mi++;
  int ni = idx - mi * (mi + 1) / 2;
  int bh = bh0 + blockIdx.y, b = bh >> 4, hd = bh & 15, g = hd >> 2;
  int m0 = mi << 7, n0 = ni << 7;
  const u16* pAh = qhi + (long)b * 2097152 + hd * 128 + (long)(m0 + r) * 2048 + c;
  const u16* pAh2 = pAh + 64 * 2048;
  const u16* pAl = qlo + (long)b * 2097152 + hd * 128 + (long)(m0 + r) * 2048 + c;
  const u16* pAl2 = pAl + 64 * 2048;
  const u16* pBh = khi + (long)b * 524288 + g * 128 + (long)(n0 + r) * 512 + c;
  const u16* pBh2 = pBh + 64 * 512;
  const u16* pBl = klo + (long)b * 524288 + g * 128 + (long)(n0 + r) * 512 + c;
  const u16* pBl2 = pBl + 64 * 512;
  { int ko = 0; STAGE_HILO(0) }
  __syncthreads();
  int cur = 0;
  for (int k0 = 0; k0 < 128; k0 += 32) {
    if (k0 + 32 < 128) { int ko = k0 + 32; STAGE_HILO(cur ^ 1) }
    mf_hilo(sAh[cur], sAl[cur], sBh[cur], sBl[cur], acc, wm, wn, lr, lk);
    __syncthreads();
    cur ^= 1;
  }
  float* Cb = sc + ((long)blockIdx.y * 1024 + m0) * 1024 + n0;
  const float scalef = 0.08838834764831845f;
#pragma unroll
  for (int i = 0; i < 4; i++)
#pragma unroll
    for (int j = 0; j < 4; j++)
#pragma unroll
      for (int rr = 0; rr < 4; rr++)
        Cb[(long)(wm + i * 16 + er + rr) * 1024 + wn + j * 16 + ec] =
            acc[i][j][rr] * scalef;
}

// attn[b][q][h][dv] = probs @ v  (B = vT[b][g][dv][t], causal K-limit); out hi/lo bf16
__global__ __launch_bounds__(256) void gemm_pv(
    const u16* __restrict__ phi, const u16* __restrict__ plo,
    const u16* __restrict__ vthi, const u16* __restrict__ vtlo,
    u16* __restrict__ athi, u16* __restrict__ atlo, int bh0) {
  HILO_PREAMBLE
  int m0 = blockIdx.x << 7;
  int bh = bh0 + blockIdx.y, b = bh >> 4, hd = bh & 15, g = hd >> 2;
  const u16* pAh = phi + (long)blockIdx.y * 1048576 + (long)(m0 + r) * 1024 + c;
  const u16* pAh2 = pAh + 64 * 1024;
  const u16* pAl = plo + (long)blockIdx.y * 1048576 + (long)(m0 + r) * 1024 + c;
  const u16* pAl2 = pAl + 64 * 1024;
  const u16* pBh = vthi + (long)(b * 4 + g) * 131072 + (long)r * 1024 + c;
  const u16* pBh2 = pBh + 64 * 1024;
  const u16* pBl = vtlo + (long)(b * 4 + g) * 131072 + (long)r * 1024 + c;
  const u16* pBl2 = pBl + 64 * 1024;
  int Klim = m0 + 128;
  { int ko = 0; STAGE_HILO(0) }
  __syncthreads();
  int cur = 0;
  for (int k0 = 0; k0 < Klim; k0 += 32) {
    if (k0 + 32 < Klim) { int ko = k0 + 32; STAGE_HILO(cur ^ 1) }
    mf_hilo(sAh[cur], sAl[cur], sBh[cur], sBl[cur], acc, wm, wn, lr, lk);
    __syncthreads();
    cur ^= 1;
  }
  long Cb = ((long)(b * 1024 + m0) * 16 + hd) * 128;
#pragma unroll
  for (int i = 0; i < 4; i++)
#pragma unroll
    for (int j = 0; j < 4; j++)
#pragma unroll
      for (int rr = 0; rr < 4; rr++) {
        u16 hh, ll;
        split2(acc[i][j][rr], hh, ll);
        long o = Cb + (long)(wm + i * 16 + er + rr) * 2048 + wn + j * 16 + ec;
        athi[o] = hh; atlo[o] = ll;
      }
}

// ---------------- bf16 MoE GEMMs --------------------------------------------

// mid[slot][F] = silu(gather(t2) @ W1T[e]^T)   (W1T: [e][4096 n][2048 k] bf16)
__global__ __launch_bounds__(256) void gemm_moe1(const u16* __restrict__ t2,
    const u16* __restrict__ W1T, const int* __restrict__ offsets,
    const int* __restrict__ counts, const int* __restrict__ ltok,
    u16* __restrict__ mid) {
  int e = blockIdx.z;
  int cnt = counts[e];
  int m0 = blockIdx.y << 7;
  if (m0 >= cnt) return;
  BF16_PREAMBLE
  int off = offsets[e];
  int n0 = blockIdx.x << 7;
  int valid = cnt - m0; if (valid > 128) valid = 128;
  int rr0 = (r < valid) ? r : 0;
  int rr1 = (r + 64 < valid) ? (r + 64) : 0;
  const u16* pA = t2 + (long)ltok[off + m0 + rr0] * 2048 + c;
  const u16* pA2 = t2 + (long)ltok[off + m0 + rr1] * 2048 + c;
  const u16* pB = W1T + (long)e * 8388608 + (long)(n0 + r) * 2048 + c;
  const u16* pB2 = pB + 64 * 2048;
  { int ko = 0; STAGE_AB(0) }
  __syncthreads();
  int cur = 0;
  for (int k0 = 0; k0 < 2048; k0 += 32) {
    if (k0 + 32 < 2048) { int ko = k0 + 32; STAGE_AB(cur ^ 1) }
    mf_bf16(sA[cur], sB[cur], acc, wm, wn, lr, lk);
    __syncthreads();
    cur ^= 1;
  }
#pragma unroll
  for (int i = 0; i < 4; i++)
#pragma unroll
    for (int j = 0; j < 4; j++)
#pragma unroll
      for (int rr = 0; rr < 4; rr++) {
        int rowl = wm + i * 16 + er + rr;
        if (rowl < valid) {
          float v = acc[i][j][rr];
          v = v / (1.0f + __expf(-v));
          mid[(long)(off + m0 + rowl) * 4096 + n0 + wn + j * 16 + ec] = f2bf(v);
        }
      }
}

// out[token] += gate * (mid @ W2T[e]^T)   (W2T: [e][2048 n][4096 k] bf16)
__global__ __launch_bounds__(256) void gemm_moe2(const u16* __restrict__ mid,
    const u16* __restrict__ W2T, const int* __restrict__ offsets,
    const int* __restrict__ counts, const int* __restrict__ ltok,
    const float* __restrict__ lgate, float* __restrict__ out) {
  int e = blockIdx.z;
  int cnt = counts[e];
  int m0 = blockIdx.y << 7;
  if (m0 >= cnt) return;
  BF16_PREAMBLE
  int off = offsets[e];
  int n0 = blockIdx.x << 7;
  int valid = cnt - m0; if (valid > 128) valid = 128;
  int rw0 = off + m0 + ((r < valid) ? r : valid - 1);
  int rw1 = off + m0 + ((r + 64 < valid) ? r + 64 : valid - 1);
  const u16* pA = mid + (long)rw0 * 4096 + c;
  const u16* pA2 = mid + (long)rw1 * 4096 + c;
  const u16* pB = W2T + (long)e * 8388608 + (long)(n0 + r) * 4096 + c;
  const u16* pB2 = pB + 64 * 4096;
  { int ko = 0; STAGE_AB(0) }
  __syncthreads();
  int cur = 0;
  for (int k0 = 0; k0 < 4096; k0 += 32) {
    if (k0 + 32 < 4096) { int ko = k0 + 32; STAGE_AB(cur ^ 1) }
    mf_bf16(sA[cur], sB[cur], acc, wm, wn, lr, lk);
    __syncthreads();
    cur ^= 1;
  }
#pragma unroll
  for (int i = 0; i < 4; i++)
#pragma unroll
    for (int j = 0; j < 4; j++)
#pragma unroll
      for (int rr = 0; rr < 4; rr++) {
        int rowl = wm + i * 16 + er + rr;
        if (rowl < valid) {
          int t = ltok[off + m0 + rowl];
          float g = lgate[off + m0 + rowl];
          atomicAdd(&out[(long)t * 2048 + n0 + wn + j * 16 + ec], g * acc[i][j][rr]);
        }
      }
}

// ---------------- launch -----------------------------------------------------
// ws layout (requires ws_size >= 192,937,984 B ~= 184 MiB):
//   attention phase [0, 192.9 MB):    sc, phi, plo, hhi/hlo, q, kk, vv,
//     qhi/qlo, khi/klo, vthi/vtlo, athi/atlo, dense weight splits
//   MoE phase (overlays dead attention scratch):
//     wbuf [0,134.2MB) = W1T then W2T; mid @134.2MB; t2 @167.8MB; misc @176.2MB
extern "C" void kernel_launch(void* const* d_in, const int* in_sizes, int n_in,
                              void* d_out, int out_size, void* d_ws, size_t ws_size,
                              hipStream_t stream) {
  (void)in_sizes; (void)n_in; (void)out_size; (void)ws_size;
  const float* x   = (const float*)d_in[0];
  const float* ln1 = (const float*)d_in[1];
  const float* Wq  = (const float*)d_in[2];
  const float* Wk  = (const float*)d_in[3];
  const float* Wv  = (const float*)d_in[4];
  const float* Wo  = (const float*)d_in[5];
  const float* ln2 = (const float*)d_in[6];
  const float* Wr  = (const float*)d_in[7];
  const float* W1  = (const float*)d_in[8];
  const float* W2  = (const float*)d_in[9];
  float* out = (float*)d_out;
  char* ws = (char*)d_ws;

  float* sc  = (float*)(ws);
  u16* phi   = (u16*)(ws + 33554432);
  u16* plo   = (u16*)(ws + 50331648);
  u16* hhi   = (u16*)(ws + 67108864);
  u16* hlo   = (u16*)(ws + 75497472);
  float* q   = (float*)(ws + 83886080);
  float* kk  = (float*)(ws + 100663296);
  float* vv  = (float*)(ws + 104857600);
  u16* qhi   = (u16*)(ws + 109051904);
  u16* qlo   = (u16*)(ws + 117440512);
  u16* khi   = (u16*)(ws + 125829120);
  u16* klo   = (u16*)(ws + 127926272);
  u16* vthi  = (u16*)(ws + 130023424);
  u16* vtlo  = (u16*)(ws + 132120576);
  u16* athi  = (u16*)(ws + 134217728);
  u16* atlo  = (u16*)(ws + 142606336);
  u16* wqh   = (u16*)(ws + 150994944);
  u16* wql   = (u16*)(ws + 159383552);
  u16* wkh   = (u16*)(ws + 167772160);
  u16* wkl   = (u16*)(ws + 169869312);
  u16* wvh   = (u16*)(ws + 171966464);
  u16* wvl   = (u16*)(ws + 174063616);
  u16* woh   = (u16*)(ws + 176160768);
  u16* wol   = (u16*)(ws + 184549376);
  // MoE-phase overlays (written only after attention scratch is dead)
  u16* wbuf  = (u16*)(ws);
  u16* mid   = (u16*)(ws + 134217728);
  u16* t2    = (u16*)(ws + 167772160);
  char* misc = ws + 176160768;
  int*   tok_e   = (int*)misc;
  float* tok_g   = (float*)(misc + 16384);
  int*   ltok    = (int*)(misc + 32768);
  float* lgate   = (float*)(misc + 49152);
  int*   counts  = (int*)(misc + 65536);
  int*   offsets = (int*)(misc + 65600);
  int*   cursor  = (int*)(misc + 65664);

  // dense weight conversion (fp32 [K][N] -> hi/lo bf16 [N][K])
  convt_split<<<dim3(64, 32), 256, 0, stream>>>(Wq, wqh, wql, 2048, 2048);
  convt_split<<<dim3(16, 32), 256, 0, stream>>>(Wk, wkh, wkl, 2048, 512);
  convt_split<<<dim3(16, 32), 256, 0, stream>>>(Wv, wvh, wvl, 2048, 512);
  convt_split<<<dim3(64, 32), 256, 0, stream>>>(Wo, woh, wol, 2048, 2048);

  rmsnorm_split<<<2048, 256, 0, stream>>>(x, ln1, hhi, hlo);
  gemm_hilo<<<dim3(16, 16), 256, 0, stream>>>(hhi, hlo, 2048, wqh, wql, 2048,
                                              nullptr, q, 2048, 2048);
  gemm_hilo<<<dim3(4, 16), 256, 0, stream>>>(hhi, hlo, 2048, wkh, wkl, 2048,
                                             nullptr, kk, 512, 2048);
  gemm_hilo<<<dim3(4, 16), 256, 0, stream>>>(hhi, hlo, 2048, wvh, wvl, 2048,
                                             nullptr, vv, 512, 2048);
  rope_split<<<8192, 256, 0, stream>>>(q, 16, qhi, qlo);
  rope_split<<<2048, 256, 0, stream>>>(kk, 4, khi, klo);
  transpose_split<<<dim3(16, 32, 2), 256, 0, stream>>>(vv, vthi, vtlo, 1024, 512);
  for (int s = 0; s < 4; s++) {
    gemm_qk<<<dim3(36, 8), 256, 0, stream>>>(qhi, qlo, khi, klo, sc, s * 8);
    softmax_split<<<8192, 256, 0, stream>>>(sc, phi, plo);
    gemm_pv<<<dim3(8, 8), 256, 0, stream>>>(phi, plo, vthi, vtlo, athi, atlo, s * 8);
  }
  gemm_hilo<<<dim3(16, 16), 256, 0, stream>>>(athi, atlo, 2048, woh, wol, 2048,
                                              x, out, 2048, 2048);
  rmsnorm_bf16<<<2048, 256, 0, stream>>>(out, ln2, t2);
  hipMemsetAsync(counts, 0, 32, stream);
  router_kernel<<<2048, 256, 0, stream>>>(out, ln2, Wr, tok_e, tok_g, counts);
  scan8<<<1, 64, 0, stream>>>(counts, offsets, cursor);
  fill_lists<<<16, 256, 0, stream>>>(tok_e, tok_g, offsets, cursor, ltok, lgate);
  // MoE: convert W1 -> wbuf (attention scratch dead), run moe1, then reuse wbuf for W2
  convt_bf16<<<dim3(128, 32, 8), 256, 0, stream>>>(W1, wbuf, 2048, 4096);
  gemm_moe1<<<dim3(32, 16, 8), 256, 0, stream>>>(t2, wbuf, offsets, counts, ltok, mid);
  convt_bf16<<<dim3(64, 64, 8), 256, 0, stream>>>(W2, wbuf, 4096, 2048);
  gemm_moe2<<<dim3(16, 16, 8), 256, 0, stream>>>(mid, wbuf, offsets, counts, ltok,
                                                 lgate, out);
}

// Round 2
// 1332.912 us; speedup vs baseline: 1.5965x; 1.1747x over previous
//
#include <hip/hip_runtime.h>

typedef unsigned short u16;
typedef __attribute__((ext_vector_type(8))) short bf16x8;
typedef __attribute__((ext_vector_type(4))) float f32x4;

__device__ __forceinline__ u16 f2bf(float f) {
  union { float f; unsigned u; } v; v.f = f;
  unsigned r = (v.u + 0x7fffu + ((v.u >> 16) & 1u)) >> 16;
  return (u16)r;
}
__device__ __forceinline__ float bf2f(u16 u) {
  union { unsigned u; float f; } v; v.u = ((unsigned)u) << 16;
  return v.f;
}
__device__ __forceinline__ void split2(float f, u16& hi, u16& lo) {
  hi = f2bf(f);
  lo = f2bf(f - bf2f(hi));
}

// ---------------- async global->LDS staging ---------------------------------
typedef const unsigned int __attribute__((address_space(1)))* gptr_t;
typedef unsigned int __attribute__((address_space(3)))* lptr_t;

__device__ __forceinline__ void gl16(const u16* g, u16* l) {
#if __has_builtin(__builtin_amdgcn_global_load_lds)
  __builtin_amdgcn_global_load_lds((gptr_t)g, (lptr_t)l, 16, 0, 0);
#else
  *reinterpret_cast<uint4*>(l) = *reinterpret_cast<const uint4*>(g);
#endif
}

// ---------------- MFMA cores -------------------------------------------------
__device__ __forceinline__ void mf_bf16(const u16* __restrict__ sA,
    const u16* __restrict__ sB, f32x4 (&acc)[4][4], int wm, int wn, int lr, int lk) {
  bf16x8 a[4], b[4];
#pragma unroll
  for (int i = 0; i < 4; i++) {
    a[i] = *reinterpret_cast<const bf16x8*>(&sA[(wm + i * 16 + lr) * 32 + lk]);
    b[i] = *reinterpret_cast<const bf16x8*>(&sB[(wn + i * 16 + lr) * 32 + lk]);
  }
#pragma unroll
  for (int i = 0; i < 4; i++)
#pragma unroll
    for (int j = 0; j < 4; j++)
      acc[i][j] = __builtin_amdgcn_mfma_f32_16x16x32_bf16(a[i], b[j], acc[i][j], 0, 0, 0);
}

__device__ __forceinline__ void mf_hilo(const u16* __restrict__ sAhp,
    const u16* __restrict__ sAlp, const u16* __restrict__ sBhp,
    const u16* __restrict__ sBlp, f32x4 (&acc)[4][4], int wm, int wn, int lr, int lk) {
  bf16x8 ah[4], al[4], bh[4], bl[4];
#pragma unroll
  for (int i = 0; i < 4; i++) {
    ah[i] = *reinterpret_cast<const bf16x8*>(&sAhp[(wm + i * 16 + lr) * 32 + lk]);
    al[i] = *reinterpret_cast<const bf16x8*>(&sAlp[(wm + i * 16 + lr) * 32 + lk]);
    bh[i] = *reinterpret_cast<const bf16x8*>(&sBhp[(wn + i * 16 + lr) * 32 + lk]);
    bl[i] = *reinterpret_cast<const bf16x8*>(&sBlp[(wn + i * 16 + lr) * 32 + lk]);
  }
#pragma unroll
  for (int i = 0; i < 4; i++)
#pragma unroll
    for (int j = 0; j < 4; j++) {
      f32x4 t = acc[i][j];
      t = __builtin_amdgcn_mfma_f32_16x16x32_bf16(al[i], bh[j], t, 0, 0, 0);
      t = __builtin_amdgcn_mfma_f32_16x16x32_bf16(ah[i], bl[j], t, 0, 0, 0);
      t = __builtin_amdgcn_mfma_f32_16x16x32_bf16(ah[i], bh[j], t, 0, 0, 0);
      acc[i][j] = t;  // lo*lo dropped: ~2^-16 relative, negligible
    }
}

#define HILO_PREAMBLE \
  __shared__ __align__(16) u16 sAh[2][4096], sAl[2][4096], sBh[2][4096], sBl[2][4096]; \
  int tid = threadIdx.x, lane = tid & 63; \
  int wm = ((tid >> 6) & 1) << 6, wn = (tid >> 7) << 6; \
  int lr = lane & 15, lk = (lane >> 4) << 3; \
  int er = (lane >> 4) << 2, ec = lane & 15; \
  int r = tid >> 2, c = (tid & 3) << 3; \
  int so = r * 32 + c, so2 = so + 2048; \
  f32x4 acc[4][4] = {};

#define STAGE_HILO(buf) \
  gl16(pAh + ko, &sAh[buf][so]); gl16(pAh2 + ko, &sAh[buf][so2]); \
  gl16(pAl + ko, &sAl[buf][so]); gl16(pAl2 + ko, &sAl[buf][so2]); \
  gl16(pBh + ko, &sBh[buf][so]); gl16(pBh2 + ko, &sBh[buf][so2]); \
  gl16(pBl + ko, &sBl[buf][so]); gl16(pBl2 + ko, &sBl[buf][so2]);

#define BF16_PREAMBLE \
  __shared__ __align__(16) u16 sA[2][4096], sB[2][4096]; \
  int tid = threadIdx.x, lane = tid & 63; \
  int wm = ((tid >> 6) & 1) << 6, wn = (tid >> 7) << 6; \
  int lr = lane & 15, lk = (lane >> 4) << 3; \
  int er = (lane >> 4) << 2, ec = lane & 15; \
  int r = tid >> 2, c = (tid & 3) << 3; \
  int so = r * 32 + c, so2 = so + 2048; \
  f32x4 acc[4][4] = {};

#define STAGE_AB(buf) \
  gl16(pA + ko, &sA[buf][so]); gl16(pA2 + ko, &sA[buf][so2]); \
  gl16(pB + ko, &sB[buf][so]); gl16(pB2 + ko, &sB[buf][so2]);

// ---------------- weight conversion kernels ----------------------------------
// fp32 W[K][N] (expert stride K*N via blockIdx.z) -> bf16 T[N][K]; 64K x 32N tiles
__global__ __launch_bounds__(256) void convt_bf16(const float* __restrict__ W,
    u16* __restrict__ T, int K, int N) {
  __shared__ float t[64][33];
  long eo = (long)blockIdx.z * K * N;
  int k0 = blockIdx.y << 6, n0 = blockIdx.x << 5;
  int tid = threadIdx.x;
  int r = tid >> 3, cc = (tid & 7) << 2;
  const float* src = W + eo + (long)(k0 + r) * N + n0 + cc;
  float4 a = *reinterpret_cast<const float4*>(src);
  float4 b = *reinterpret_cast<const float4*>(src + (long)32 * N);
  t[r][cc] = a.x; t[r][cc + 1] = a.y; t[r][cc + 2] = a.z; t[r][cc + 3] = a.w;
  t[r + 32][cc] = b.x; t[r + 32][cc + 1] = b.y; t[r + 32][cc + 2] = b.z; t[r + 32][cc + 3] = b.w;
  __syncthreads();
  int n = tid >> 3, kc = (tid & 7) << 3;
  __align__(16) u16 h[8];
#pragma unroll
  for (int i = 0; i < 8; i++) h[i] = f2bf(t[kc + i][n]);
  *reinterpret_cast<uint4*>(&T[eo + (long)(n0 + n) * K + k0 + kc]) =
      *reinterpret_cast<uint4*>(h);
}

// fp32 W[K][N] -> hi/lo bf16 T[N][K]
__global__ __launch_bounds__(256) void convt_split(const float* __restrict__ W,
    u16* __restrict__ Thi, u16* __restrict__ Tlo, int K, int N) {
  __shared__ float t[64][33];
  int k0 = blockIdx.y << 6, n0 = blockIdx.x << 5;
  int tid = threadIdx.x;
  int r = tid >> 3, cc = (tid & 7) << 2;
  const float* src = W + (long)(k0 + r) * N + n0 + cc;
  float4 a = *reinterpret_cast<const float4*>(src);
  float4 b = *reinterpret_cast<const float4*>(src + (long)32 * N);
  t[r][cc] = a.x; t[r][cc + 1] = a.y; t[r][cc + 2] = a.z; t[r][cc + 3] = a.w;
  t[r + 32][cc] = b.x; t[r + 32][cc + 1] = b.y; t[r + 32][cc + 2] = b.z; t[r + 32][cc + 3] = b.w;
  __syncthreads();
  int n = tid >> 3, kc = (tid & 7) << 3;
  __align__(16) u16 h[8], l[8];
#pragma unroll
  for (int i = 0; i < 8; i++) split2(t[kc + i][n], h[i], l[i]);
  long o = (long)(n0 + n) * K + k0 + kc;
  *reinterpret_cast<uint4*>(&Thi[o]) = *reinterpret_cast<uint4*>(h);
  *reinterpret_cast<uint4*>(&Tlo[o]) = *reinterpret_cast<uint4*>(l);
}

// ---------------- elementwise / small kernels -------------------------------

// rmsnorm row (D=2048 fp32) -> hi/lo bf16 (attention input)
__global__ __launch_bounds__(256) void rmsnorm_split(const float* __restrict__ x,
    const float* __restrict__ w, u16* __restrict__ ohi, u16* __restrict__ olo) {
  __shared__ float lbuf[4];
  int tid = threadIdx.x;
  long base = (long)blockIdx.x * 2048;
  float4 v0 = *reinterpret_cast<const float4*>(&x[base + tid * 8]);
  float4 v1 = *reinterpret_cast<const float4*>(&x[base + tid * 8 + 4]);
  float ss = v0.x * v0.x + v0.y * v0.y + v0.z * v0.z + v0.w * v0.w +
             v1.x * v1.x + v1.y * v1.y + v1.z * v1.z + v1.w * v1.w;
  for (int off = 32; off; off >>= 1) ss += __shfl_down(ss, off);
  if ((tid & 63) == 0) lbuf[tid >> 6] = ss;
  __syncthreads();
  float tot = lbuf[0] + lbuf[1] + lbuf[2] + lbuf[3];
  float scale = 1.0f / sqrtf(tot * (1.0f / 2048.0f) + 1e-6f);
  float4 w0 = *reinterpret_cast<const float4*>(&w[tid * 8]);
  float4 w1 = *reinterpret_cast<const float4*>(&w[tid * 8 + 4]);
  float f[8] = {v0.x * scale * w0.x, v0.y * scale * w0.y, v0.z * scale * w0.z,
                v0.w * scale * w0.w, v1.x * scale * w1.x, v1.y * scale * w1.y,
                v1.z * scale * w1.z, v1.w * scale * w1.w};
  __align__(16) u16 h[8], l[8];
#pragma unroll
  for (int i = 0; i < 8; i++) split2(f[i], h[i], l[i]);
  *reinterpret_cast<uint4*>(&ohi[base + tid * 8]) = *reinterpret_cast<uint4*>(h);
  *reinterpret_cast<uint4*>(&olo[base + tid * 8]) = *reinterpret_cast<uint4*>(l);
}

// rmsnorm row -> bf16 (MoE input)
__global__ __launch_bounds__(256) void rmsnorm_bf16(const float* __restrict__ x,
    const float* __restrict__ w, u16* __restrict__ o) {
  __shared__ float lbuf[4];
  int tid = threadIdx.x;
  long base = (long)blockIdx.x * 2048;
  float4 v0 = *reinterpret_cast<const float4*>(&x[base + tid * 8]);
  float4 v1 = *reinterpret_cast<const float4*>(&x[base + tid * 8 + 4]);
  float ss = v0.x * v0.x + v0.y * v0.y + v0.z * v0.z + v0.w * v0.w +
             v1.x * v1.x + v1.y * v1.y + v1.z * v1.z + v1.w * v1.w;
  for (int off = 32; off; off >>= 1) ss += __shfl_down(ss, off);
  if ((tid & 63) == 0) lbuf[tid >> 6] = ss;
  __syncthreads();
  float tot = lbuf[0] + lbuf[1] + lbuf[2] + lbuf[3];
  float scale = 1.0f / sqrtf(tot * (1.0f / 2048.0f) + 1e-6f);
  float4 w0 = *reinterpret_cast<const float4*>(&w[tid * 8]);
  float4 w1 = *reinterpret_cast<const float4*>(&w[tid * 8 + 4]);
  ushort4 o0, o1;
  o0.x = f2bf(v0.x * scale * w0.x); o0.y = f2bf(v0.y * scale * w0.y);
  o0.z = f2bf(v0.z * scale * w0.z); o0.w = f2bf(v0.w * scale * w0.w);
  o1.x = f2bf(v1.x * scale * w1.x); o1.y = f2bf(v1.y * scale * w1.y);
  o1.z = f2bf(v1.z * scale * w1.z); o1.w = f2bf(v1.w * scale * w1.w);
  *reinterpret_cast<ushort4*>(&o[base + tid * 8]) = o0;
  *reinterpret_cast<ushort4*>(&o[base + tid * 8 + 4]) = o1;
}

// RoPE reading sum of two fp32 split-K halves laid [row][ld] with col base;
// writes hi/lo bf16 in compact [unit][128] layout. One 64-lane unit per head-row.
__global__ __launch_bounds__(256) void rope2_split(const float* __restrict__ x0,
    const float* __restrict__ x1, int hshift, int hmask, long ld, long colbase,
    u16* __restrict__ ohi, u16* __restrict__ olo) {
  int unit = blockIdx.x * 4 + (threadIdx.x >> 6);
  int lane = threadIdx.x & 63;
  int s = (unit >> hshift) & 1023;
  long src = (long)(unit >> hshift) * ld + colbase + ((long)(unit & hmask) << 7);
  float a1 = x0[src + lane] + x1[src + lane];
  float a2 = x0[src + lane + 64] + x1[src + lane + 64];
  float ang = (float)s * exp2f((float)lane * (-13.287712379549449f / 64.0f));
  float sn, cs;
  sincosf(ang, &sn, &cs);
  long o = (long)unit * 128 + lane;
  u16 hh, ll;
  split2(a1 * cs - a2 * sn, hh, ll);
  ohi[o] = hh; olo[o] = ll;
  split2(a1 * sn + a2 * cs, hh, ll);
  ohi[o + 64] = hh; olo[o + 64] = ll;
}

// transpose (sum of two fp32 halves) [R][C] (ld) -> hi/lo bf16 [C][R] per batch z
__global__ __launch_bounds__(256) void transpose2_split(const float* __restrict__ in0,
    const float* __restrict__ in1, long ld, long bstride, u16* __restrict__ ohi,
    u16* __restrict__ olo, int R, int C) {
  __shared__ float tile[32][33];
  long bi = (long)blockIdx.z * bstride;
  long bo = (long)blockIdx.z * R * C;
  int r0 = blockIdx.y * 32, c0 = blockIdx.x * 32;
  int r = threadIdx.x >> 5, c = threadIdx.x & 31;
#pragma unroll
  for (int i = 0; i < 4; i++) {
    long a = bi + (long)(r0 + r + i * 8) * ld + c0 + c;
    tile[r + i * 8][c] = in0[a] + in1[a];
  }
  __syncthreads();
#pragma unroll
  for (int i = 0; i < 4; i++) {
    u16 hh, ll;
    split2(tile[c][r + i * 8], hh, ll);
    long o = bo + (long)(c0 + r + i * 8) * R + r0 + c;
    ohi[o] = hh; olo[o] = ll;
  }
}

// causal softmax in-place on hi/lo bf16 scores row (len 1024)
__global__ __launch_bounds__(256) void softmax_hilo(u16* __restrict__ ph,
    u16* __restrict__ pl) {
  __shared__ float lbuf[4];
  long row = blockIdx.x;
  int q = (int)(row & 1023);
  int tid = threadIdx.x;
  int valid = q + 1;
  int pend = (q & ~127) + 128;
  int t0 = tid * 4;
  long base = row * 1024 + t0;
  ushort4 vh = *reinterpret_cast<ushort4*>(&ph[base]);
  ushort4 vl = *reinterpret_cast<ushort4*>(&pl[base]);
  float v[4] = {bf2f(vh.x) + bf2f(vl.x), bf2f(vh.y) + bf2f(vl.y),
                bf2f(vh.z) + bf2f(vl.z), bf2f(vh.w) + bf2f(vl.w)};
  float mx = -1e30f;
#pragma unroll
  for (int i = 0; i < 4; i++) {
    if (t0 + i >= valid) v[i] = -1e30f;
    mx = fmaxf(mx, v[i]);
  }
  for (int off = 32; off; off >>= 1) mx = fmaxf(mx, __shfl_down(mx, off));
  if ((tid & 63) == 0) lbuf[tid >> 6] = mx;
  __syncthreads();
  float m = fmaxf(fmaxf(lbuf[0], lbuf[1]), fmaxf(lbuf[2], lbuf[3]));
  __syncthreads();
  float sum = 0.0f;
#pragma unroll
  for (int i = 0; i < 4; i++) {
    float e = (t0 + i < valid) ? expf(v[i] - m) : 0.0f;
    v[i] = e;
    sum += e;
  }
  for (int off = 32; off; off >>= 1) sum += __shfl_down(sum, off);
  if ((tid & 63) == 0) lbuf[tid >> 6] = sum;
  __syncthreads();
  float inv = 1.0f / (lbuf[0] + lbuf[1] + lbuf[2] + lbuf[3]);
  if (t0 < pend) {
    ushort4 oh, ol;
    u16 hh, ll;
    split2(v[0] * inv, hh, ll); oh.x = hh; ol.x = ll;
    split2(v[1] * inv, hh, ll); oh.y = hh; ol.y = ll;
    split2(v[2] * inv, hh, ll); oh.z = hh; ol.z = ll;
    split2(v[3] * inv, hh, ll); oh.w = hh; ol.w = ll;
    *reinterpret_cast<ushort4*>(&ph[base]) = oh;
    *reinterpret_cast<ushort4*>(&pl[base]) = ol;
  }
}

// fp32 attn [2048][2048] -> hi/lo bf16
__global__ __launch_bounds__(256) void split_attn(const float* __restrict__ a,
    u16* __restrict__ ohi, u16* __restrict__ olo) {
  long i = ((long)blockIdx.x * 256 + threadIdx.x) * 8;
  float4 v0 = *reinterpret_cast<const float4*>(&a[i]);
  float4 v1 = *reinterpret_cast<const float4*>(&a[i + 4]);
  float f[8] = {v0.x, v0.y, v0.z, v0.w, v1.x, v1.y, v1.z, v1.w};
  __align__(16) u16 h[8], l[8];
#pragma unroll
  for (int j = 0; j < 8; j++) split2(f[j], h[j], l[j]);
  *reinterpret_cast<uint4*>(&ohi[i]) = *reinterpret_cast<uint4*>(h);
  *reinterpret_cast<uint4*>(&olo[i]) = *reinterpret_cast<uint4*>(l);
}

// router: fp32 rmsnorm of out row + fp32 logits, top-2, gates, counts
__global__ __launch_bounds__(256) void router_kernel(const float* __restrict__ xo,
    const float* __restrict__ w, const float* __restrict__ Wr,
    int* __restrict__ tok_e, float* __restrict__ tok_g, int* __restrict__ counts) {
  __shared__ float lbuf[32];
  int tid = threadIdx.x;
  long base = (long)blockIdx.x * 2048;
  float4 v0 = *reinterpret_cast<const float4*>(&xo[base + tid * 8]);
  float4 v1 = *reinterpret_cast<const float4*>(&xo[base + tid * 8 + 4]);
  float ss = v0.x * v0.x + v0.y * v0.y + v0.z * v0.z + v0.w * v0.w +
             v1.x * v1.x + v1.y * v1.y + v1.z * v1.z + v1.w * v1.w;
  for (int off = 32; off; off >>= 1) ss += __shfl_down(ss, off);
  if ((tid & 63) == 0) lbuf[tid >> 6] = ss;
  __syncthreads();
  float tot = lbuf[0] + lbuf[1] + lbuf[2] + lbuf[3];
  float scale = 1.0f / sqrtf(tot * (1.0f / 2048.0f) + 1e-6f);
  __syncthreads();
  float4 w0 = *reinterpret_cast<const float4*>(&w[tid * 8]);
  float4 w1 = *reinterpret_cast<const float4*>(&w[tid * 8 + 4]);
  float h[8] = {v0.x * scale * w0.x, v0.y * scale * w0.y, v0.z * scale * w0.z,
                v0.w * scale * w0.w, v1.x * scale * w1.x, v1.y * scale * w1.y,
                v1.z * scale * w1.z, v1.w * scale * w1.w};
  float part[8] = {0, 0, 0, 0, 0, 0, 0, 0};
#pragma unroll
  for (int j = 0; j < 8; j++) {
    const float* wr = Wr + (long)(tid * 8 + j) * 8;
    float4 a = *reinterpret_cast<const float4*>(wr);
    float4 b = *reinterpret_cast<const float4*>(wr + 4);
    part[0] += h[j] * a.x; part[1] += h[j] * a.y;
    part[2] += h[j] * a.z; part[3] += h[j] * a.w;
    part[4] += h[j] * b.x; part[5] += h[j] * b.y;
    part[6] += h[j] * b.z; part[7] += h[j] * b.w;
  }
#pragma unroll
  for (int e = 0; e < 8; e++) {
    float s = part[e];
    for (int off = 32; off; off >>= 1) s += __shfl_down(s, off);
    if ((tid & 63) == 0) lbuf[(tid >> 6) * 8 + e] = s;
  }
  __syncthreads();
  if (tid == 0) {
    float lg[8];
#pragma unroll
    for (int e = 0; e < 8; e++)
      lg[e] = lbuf[e] + lbuf[8 + e] + lbuf[16 + e] + lbuf[24 + e];
    int e1 = 0;
    for (int e = 1; e < 8; e++) if (lg[e] > lg[e1]) e1 = e;
    int e2 = -1;
    for (int e = 0; e < 8; e++) if (e != e1 && (e2 < 0 || lg[e] > lg[e2])) e2 = e;
    float ex = __expf(lg[e2] - lg[e1]);
    float g1 = 1.0f / (1.0f + ex);
    tok_e[blockIdx.x * 2] = e1; tok_e[blockIdx.x * 2 + 1] = e2;
    tok_g[blockIdx.x * 2] = g1; tok_g[blockIdx.x * 2 + 1] = 1.0f - g1;
    atomicAdd(&counts[e1], 1);
    atomicAdd(&counts[e2], 1);
  }
}

__global__ void scan8(const int* __restrict__ counts, int* __restrict__ offsets,
                      int* __restrict__ cursor) {
  if (threadIdx.x == 0) {
    int off = 0;
    for (int e = 0; e < 8; e++) { offsets[e] = off; off += counts[e]; cursor[e] = 0; }
  }
}

__global__ __launch_bounds__(256) void fill_lists(const int* __restrict__ tok_e,
    const float* __restrict__ tok_g, const int* __restrict__ offsets,
    int* __restrict__ cursor, int* __restrict__ ltok, float* __restrict__ lgate) {
  int idx = blockIdx.x * 256 + threadIdx.x;  // 4096 slots
  int token = idx >> 1;
  int e = tok_e[idx];
  float g = tok_g[idx];
  int pos = atomicAdd(&cursor[e], 1);
  int j = offsets[e] + pos;
  ltok[j] = token;
  lgate[j] = g;
}

// ---------------- attention GEMMs (hilo) -------------------------------------

// fused QKV projection, split-K2: C[z][2048][3072], z = K-half (sum by consumers)
__global__ __launch_bounds__(256) void gemm_qkv(
    const u16* __restrict__ Ahi, const u16* __restrict__ Alo,
    const u16* __restrict__ Bhi, const u16* __restrict__ Blo,
    float* __restrict__ C0, float* __restrict__ C1) {
  HILO_PREAMBLE
  int m0 = blockIdx.y << 7, n0 = blockIdx.x << 7;
  long kb = (long)blockIdx.z << 10;
  const u16* pAh = Ahi + (long)(m0 + r) * 2048 + kb + c;  const u16* pAh2 = pAh + 64 * 2048;
  const u16* pAl = Alo + (long)(m0 + r) * 2048 + kb + c;  const u16* pAl2 = pAl + 64 * 2048;
  const u16* pBh = Bhi + (long)(n0 + r) * 2048 + kb + c;  const u16* pBh2 = pBh + 64 * 2048;
  const u16* pBl = Blo + (long)(n0 + r) * 2048 + kb + c;  const u16* pBl2 = pBl + 64 * 2048;
  { int ko = 0; STAGE_HILO(0) }
  __syncthreads();
  int cur = 0;
  for (int k0 = 0; k0 < 1024; k0 += 32) {
    if (k0 + 32 < 1024) { int ko = k0 + 32; STAGE_HILO(cur ^ 1) }
    mf_hilo(sAh[cur], sAl[cur], sBh[cur], sBl[cur], acc, wm, wn, lr, lk);
    __syncthreads();
    cur ^= 1;
  }
  float* C = blockIdx.z ? C1 : C0;
#pragma unroll
  for (int i = 0; i < 4; i++)
#pragma unroll
    for (int j = 0; j < 4; j++)
#pragma unroll
      for (int rr = 0; rr < 4; rr++)
        C[(long)(m0 + wm + i * 16 + er + rr) * 3072 + n0 + wn + j * 16 + ec] =
            acc[i][j][rr];
}

// Wo projection, split-K2 via z: atomicAdd into zeroed C; z==0 adds resid x
__global__ __launch_bounds__(256) void gemm_wo(
    const u16* __restrict__ Ahi, const u16* __restrict__ Alo,
    const u16* __restrict__ Bhi, const u16* __restrict__ Blo,
    const float* __restrict__ resid, float* __restrict__ C) {
  HILO_PREAMBLE
  int m0 = blockIdx.y << 7, n0 = blockIdx.x << 7;
  long kb = (long)blockIdx.z << 10;
  const u16* pAh = Ahi + (long)(m0 + r) * 2048 + kb + c;  const u16* pAh2 = pAh + 64 * 2048;
  const u16* pAl = Alo + (long)(m0 + r) * 2048 + kb + c;  const u16* pAl2 = pAl + 64 * 2048;
  const u16* pBh = Bhi + (long)(n0 + r) * 2048 + kb + c;  const u16* pBh2 = pBh + 64 * 2048;
  const u16* pBl = Blo + (long)(n0 + r) * 2048 + kb + c;  const u16* pBl2 = pBl + 64 * 2048;
  { int ko = 0; STAGE_HILO(0) }
  __syncthreads();
  int cur = 0;
  for (int k0 = 0; k0 < 1024; k0 += 32) {
    if (k0 + 32 < 1024) { int ko = k0 + 32; STAGE_HILO(cur ^ 1) }
    mf_hilo(sAh[cur], sAl[cur], sBh[cur], sBl[cur], acc, wm, wn, lr, lk);
    __syncthreads();
    cur ^= 1;
  }
  int addres = (blockIdx.z == 0);
#pragma unroll
  for (int i = 0; i < 4; i++)
#pragma unroll
    for (int j = 0; j < 4; j++)
#pragma unroll
      for (int rr = 0; rr < 4; rr++) {
        long idx = (long)(m0 + wm + i * 16 + er + rr) * 2048 + n0 + wn + j * 16 + ec;
        float v = acc[i][j][rr];
        if (addres) v += resid[idx];
        atomicAdd(&C[idx], v);
      }
}

// scores: [bh][q][t] hi/lo bf16 = (q . k) * DK^-0.5, lower-triangular tile grid
__global__ __launch_bounds__(256) void gemm_qk(
    const u16* __restrict__ qhi, const u16* __restrict__ qlo,
    const u16* __restrict__ khi, const u16* __restrict__ klo,
    u16* __restrict__ schi, u16* __restrict__ sclo) {
  HILO_PREAMBLE
  int idx = blockIdx.x, mi = 0;
  while ((mi + 1) * (mi + 2) / 2 <= idx) mi++;
  int ni = idx - mi * (mi + 1) / 2;
  int bh = blockIdx.y, b = bh >> 4, hd = bh & 15, g = hd >> 2;
  int m0 = mi << 7, n0 = ni << 7;
  const u16* pAh = qhi + (long)b * 2097152 + hd * 128 + (long)(m0 + r) * 2048 + c;
  const u16* pAh2 = pAh + 64 * 2048;
  const u16* pAl = qlo + (long)b * 2097152 + hd * 128 + (long)(m0 + r) * 2048 + c;
  const u16* pAl2 = pAl + 64 * 2048;
  const u16* pBh = khi + (long)b * 524288 + g * 128 + (long)(n0 + r) * 512 + c;
  const u16* pBh2 = pBh + 64 * 512;
  const u16* pBl = klo + (long)b * 524288 + g * 128 + (long)(n0 + r) * 512 + c;
  const u16* pBl2 = pBl + 64 * 512;
  { int ko = 0; STAGE_HILO(0) }
  __syncthreads();
  int cur = 0;
  for (int k0 = 0; k0 < 128; k0 += 32) {
    if (k0 + 32 < 128) { int ko = k0 + 32; STAGE_HILO(cur ^ 1) }
    mf_hilo(sAh[cur], sAl[cur], sBh[cur], sBl[cur], acc, wm, wn, lr, lk);
    __syncthreads();
    cur ^= 1;
  }
  long Cb = (long)bh * 1048576 + (long)m0 * 1024 + n0;
  const float scalef = 0.08838834764831845f;
#pragma unroll
  for (int i = 0; i < 4; i++)
#pragma unroll
    for (int j = 0; j < 4; j++)
#pragma unroll
      for (int rr = 0; rr < 4; rr++) {
        u16 hh, ll;
        split2(acc[i][j][rr] * scalef, hh, ll);
        long o = Cb + (long)(wm + i * 16 + er + rr) * 1024 + wn + j * 16 + ec;
        schi[o] = hh; sclo[o] = ll;
      }
}

// PV: triangular (m-tile, k-tile) decomposition; fp32 atomic accumulation
__global__ __launch_bounds__(256) void gemm_pv_tri(
    const u16* __restrict__ phi, const u16* __restrict__ plo,
    const u16* __restrict__ vthi, const u16* __restrict__ vtlo,
    float* __restrict__ attnf) {
  HILO_PREAMBLE
  int idx = blockIdx.x, mi = 0;
  while ((mi + 1) * (mi + 2) / 2 <= idx) mi++;
  int ki = idx - mi * (mi + 1) / 2;
  int bh = blockIdx.y, b = bh >> 4, hd = bh & 15, g = hd >> 2;
  int m0 = mi << 7;
  long kb = (long)ki << 7;
  const u16* pAh = phi + (long)bh * 1048576 + (long)(m0 + r) * 1024 + kb + c;
  const u16* pAh2 = pAh + 64 * 1024;
  const u16* pAl = plo + (long)bh * 1048576 + (long)(m0 + r) * 1024 + kb + c;
  const u16* pAl2 = pAl + 64 * 1024;
  const u16* pBh = vthi + (long)(b * 4 + g) * 131072 + (long)r * 1024 + kb + c;
  const u16* pBh2 = pBh + 64 * 1024;
  const u16* pBl = vtlo + (long)(b * 4 + g) * 131072 + (long)r * 1024 + kb + c;
  const u16* pBl2 = pBl + 64 * 1024;
  { int ko = 0; STAGE_HILO(0) }
  __syncthreads();
  int cur = 0;
  for (int k0 = 0; k0 < 128; k0 += 32) {
    if (k0 + 32 < 128) { int ko = k0 + 32; STAGE_HILO(cur ^ 1) }
    mf_hilo(sAh[cur], sAl[cur], sBh[cur], sBl[cur], acc, wm, wn, lr, lk);
    __syncthreads();
    cur ^= 1;
  }
  long Cb = ((long)(b * 1024 + m0) * 16 + hd) * 128;
#pragma unroll
  for (int i = 0; i < 4; i++)
#pragma unroll
    for (int j = 0; j < 4; j++)
#pragma unroll
      for (int rr = 0; rr < 4; rr++)
        atomicAdd(&attnf[Cb + (long)(wm + i * 16 + er + rr) * 2048 + wn + j * 16 + ec],
                  acc[i][j][rr]);
}

// ---------------- bf16 MoE GEMMs --------------------------------------------

// mid[slot][F] = silu(gather(t2) @ W1T[e]^T)   (W1T: [e][4096 n][2048 k] bf16)
__global__ __launch_bounds__(256) void gemm_moe1(const u16* __restrict__ t2,
    const u16* __restrict__ W1T, const int* __restrict__ offsets,
    const int* __restrict__ counts, const int* __restrict__ ltok,
    u16* __restrict__ mid) {
  int e = blockIdx.z;
  int cnt = counts[e];
  int m0 = blockIdx.y << 7;
  if (m0 >= cnt) return;
  BF16_PREAMBLE
  int off = offsets[e];
  int n0 = blockIdx.x << 7;
  int valid = cnt - m0; if (valid > 128) valid = 128;
  int rr0 = (r < valid) ? r : 0;
  int rr1 = (r + 64 < valid) ? (r + 64) : 0;
  const u16* pA = t2 + (long)ltok[off + m0 + rr0] * 2048 + c;
  const u16* pA2 = t2 + (long)ltok[off + m0 + rr1] * 2048 + c;
  const u16* pB = W1T + (long)e * 8388608 + (long)(n0 + r) * 2048 + c;
  const u16* pB2 = pB + 64 * 2048;
  { int ko = 0; STAGE_AB(0) }
  __syncthreads();
  int cur = 0;
  for (int k0 = 0; k0 < 2048; k0 += 32) {
    if (k0 + 32 < 2048) { int ko = k0 + 32; STAGE_AB(cur ^ 1) }
    mf_bf16(sA[cur], sB[cur], acc, wm, wn, lr, lk);
    __syncthreads();
    cur ^= 1;
  }
#pragma unroll
  for (int i = 0; i < 4; i++)
#pragma unroll
    for (int j = 0; j < 4; j++)
#pragma unroll
      for (int rr = 0; rr < 4; rr++) {
        int rowl = wm + i * 16 + er + rr;
        if (rowl < valid) {
          float v = acc[i][j][rr];
          v = v / (1.0f + __expf(-v));
          mid[(long)(off + m0 + rowl) * 4096 + n0 + wn + j * 16 + ec] = f2bf(v);
        }
      }
}

// out[token] += gate * (mid @ W2T[e]^T), split-K2 via y  (W2T: [e][2048 n][4096 k])
__global__ __launch_bounds__(256) void gemm_moe2(const u16* __restrict__ mid,
    const u16* __restrict__ W2T, const int* __restrict__ offsets,
    const int* __restrict__ counts, const int* __restrict__ ltok,
    const float* __restrict__ lgate, float* __restrict__ out) {
  int e = blockIdx.z;
  int cnt = counts[e];
  int mt = blockIdx.y >> 1, ks = blockIdx.y & 1;
  int m0 = mt << 7;
  if (m0 >= cnt) return;
  BF16_PREAMBLE
  int off = offsets[e];
  int n0 = blockIdx.x << 7;
  long kb = (long)ks << 11;
  int valid = cnt - m0; if (valid > 128) valid = 128;
  int rw0 = off + m0 + ((r < valid) ? r : valid - 1);
  int rw1 = off + m0 + ((r + 64 < valid) ? r + 64 : valid - 1);
  const u16* pA = mid + (long)rw0 * 4096 + kb + c;
  const u16* pA2 = mid + (long)rw1 * 4096 + kb + c;
  const u16* pB = W2T + (long)e * 8388608 + (long)(n0 + r) * 4096 + kb + c;
  const u16* pB2 = pB + 64 * 4096;
  { int ko = 0; STAGE_AB(0) }
  __syncthreads();
  int cur = 0;
  for (int k0 = 0; k0 < 2048; k0 += 32) {
    if (k0 + 32 < 2048) { int ko = k0 + 32; STAGE_AB(cur ^ 1) }
    mf_bf16(sA[cur], sB[cur], acc, wm, wn, lr, lk);
    __syncthreads();
    cur ^= 1;
  }
#pragma unroll
  for (int i = 0; i < 4; i++)
#pragma unroll
    for (int j = 0; j < 4; j++)
#pragma unroll
      for (int rr = 0; rr < 4; rr++) {
        int rowl = wm + i * 16 + er + rr;
        if (rowl < valid) {
          int t = ltok[off + m0 + rowl];
          float g = lgate[off + m0 + rowl];
          atomicAdd(&out[(long)t * 2048 + n0 + wn + j * 16 + ec], g * acc[i][j][rr]);
        }
      }
}

// ---------------- launch -----------------------------------------------------
// ws layout (requires ws_size >= 192,937,984 B, same as previous round):
// attention phase:
//   [0,134.2M) score region, early-phase overlays before gemm_qk writes it:
//     hhi@0 hlo@8.4M | qkv0@16.8M qkv1@41.9M | wqkvh@67.1M wqkvl@79.7M
//     schi@0(67.1M) sclo@67.1M  (written by gemm_qk after all above are dead)
//   athi@134.2M atlo@142.6M | qhi@151.0M qlo@159.4M | khi/klo/vthi/vtlo@167.8M
//   attnf@151.0M (over dead qhi/qlo, after gemm_qk) | woh@176.2M wol@184.5M
// MoE phase overlays: wbuf@0(134.2M) mid@134.2M t2@167.8M misc@176.2M(dead woh)
extern "C" void kernel_launch(void* const* d_in, const int* in_sizes, int n_in,
                              void* d_out, int out_size, void* d_ws, size_t ws_size,
                              hipStream_t stream) {
  (void)in_sizes; (void)n_in; (void)out_size; (void)ws_size;
  const float* x   = (const float*)d_in[0];
  const float* ln1 = (const float*)d_in[1];
  const float* Wq  = (const float*)d_in[2];
  const float* Wk  = (const float*)d_in[3];
  const float* Wv  = (const float*)d_in[4];
  const float* Wo  = (const float*)d_in[5];
  const float* ln2 = (const float*)d_in[6];
  const float* Wr  = (const float*)d_in[7];
  const float* W1  = (const float*)d_in[8];
  const float* W2  = (const float*)d_in[9];
  float* out = (float*)d_out;
  char* ws = (char*)d_ws;

  u16* hhi    = (u16*)(ws);
  u16* hlo    = (u16*)(ws + 8388608);
  float* qkv0 = (float*)(ws + 16777216);
  float* qkv1 = (float*)(ws + 41943040);
  u16* wqkvh  = (u16*)(ws + 67108864);
  u16* wqkvl  = (u16*)(ws + 79691776);
  u16* schi   = (u16*)(ws);
  u16* sclo   = (u16*)(ws + 67108864);
  u16* athi   = (u16*)(ws + 134217728);
  u16* atlo   = (u16*)(ws + 142606336);
  u16* qhi    = (u16*)(ws + 150994944);
  u16* qlo    = (u16*)(ws + 159383552);
  float* attnf = (float*)(ws + 150994944);
  u16* khi    = (u16*)(ws + 167772160);
  u16* klo    = (u16*)(ws + 169869312);
  u16* vthi   = (u16*)(ws + 171966464);
  u16* vtlo   = (u16*)(ws + 174063616);
  u16* woh    = (u16*)(ws + 176160768);
  u16* wol    = (u16*)(ws + 184549376);
  // MoE-phase overlays
  u16* wbuf = (u16*)(ws);
  u16* mid  = (u16*)(ws + 134217728);
  u16* t2   = (u16*)(ws + 167772160);
  char* misc = ws + 176160768;  // over woh (dead after gemm_wo)
  int*   tok_e   = (int*)misc;
  float* tok_g   = (float*)(misc + 16384);
  int*   ltok    = (int*)(misc + 32768);
  float* lgate   = (float*)(misc + 49152);
  int*   counts  = (int*)(misc + 65536);
  int*   offsets = (int*)(misc + 65600);
  int*   cursor  = (int*)(misc + 65664);

  // fused QKV weight: B^T rows [0,2048)=Wq^T, [2048,2560)=Wk^T, [2560,3072)=Wv^T
  convt_split<<<dim3(64, 32), 256, 0, stream>>>(Wq, wqkvh, wqkvl, 2048, 2048);
  convt_split<<<dim3(16, 32), 256, 0, stream>>>(Wk, wqkvh + 2048 * 2048,
                                                wqkvl + 2048 * 2048, 2048, 512);
  convt_split<<<dim3(16, 32), 256, 0, stream>>>(Wv, wqkvh + 2560 * 2048,
                                                wqkvl + 2560 * 2048, 2048, 512);
  convt_split<<<dim3(64, 32), 256, 0, stream>>>(Wo, woh, wol, 2048, 2048);

  rmsnorm_split<<<2048, 256, 0, stream>>>(x, ln1, hhi, hlo);
  gemm_qkv<<<dim3(24, 16, 2), 256, 0, stream>>>(hhi, hlo, wqkvh, wqkvl, qkv0, qkv1);
  rope2_split<<<8192, 256, 0, stream>>>(qkv0, qkv1, 4, 15, 3072, 0, qhi, qlo);
  rope2_split<<<2048, 256, 0, stream>>>(qkv0, qkv1, 2, 3, 3072, 2048, khi, klo);
  transpose2_split<<<dim3(16, 32, 2), 256, 0, stream>>>(
      qkv0 + 2560, qkv1 + 2560, 3072, 3145728, vthi, vtlo, 1024, 512);
  gemm_qk<<<dim3(36, 32), 256, 0, stream>>>(qhi, qlo, khi, klo, schi, sclo);
  softmax_hilo<<<32768, 256, 0, stream>>>(schi, sclo);
  hipMemsetAsync(attnf, 0, 16777216, stream);
  gemm_pv_tri<<<dim3(36, 32), 256, 0, stream>>>(schi, sclo, vthi, vtlo, attnf);
  split_attn<<<2048, 256, 0, stream>>>(attnf, athi, atlo);
  hipMemsetAsync(out, 0, 16777216, stream);
  gemm_wo<<<dim3(16, 16, 2), 256, 0, stream>>>(athi, atlo, woh, wol, x, out);

  rmsnorm_bf16<<<2048, 256, 0, stream>>>(out, ln2, t2);
  hipMemsetAsync(counts, 0, 32, stream);
  router_kernel<<<2048, 256, 0, stream>>>(out, ln2, Wr, tok_e, tok_g, counts);
  scan8<<<1, 64, 0, stream>>>(counts, offsets, cursor);
  fill_lists<<<16, 256, 0, stream>>>(tok_e, tok_g, offsets, cursor, ltok, lgate);
  convt_bf16<<<dim3(128, 32, 8), 256, 0, stream>>>(W1, wbuf, 2048, 4096);
  gemm_moe1<<<dim3(32, 16, 8), 256, 0, stream>>>(t2, wbuf, offsets, counts, ltok, mid);
  convt_bf16<<<dim3(64, 64, 8), 256, 0, stream>>>(W2, wbuf, 4096, 2048);
  gemm_moe2<<<dim3(16, 32, 8), 256, 0, stream>>>(mid, wbuf, offsets, counts, ltok,
                                                 lgate, out);
}